// Round 6
// baseline (6716.271 us; speedup 1.0000x reference)
//
#include <hip/hip_runtime.h>

// Per-channel LSTM (input_size=1) + per-channel Linear(H,1), fully fused.
// B=512, T=1024, C=64, H=128.
// Round 12: instruction-level MFMA/VALU interleave via sched_group_barrier.
//   R11 result: dur 5504us, VGPR 128 clean, VALUBusy 70 + MfmaUtil 32 ~= 100%
//   -> pipes STILL serial: compiler emits 16-MFMA cluster then act cluster;
//   barrier-locked waves starve one pipe per cluster. m114: separate pipes
//   CAN co-issue. Fix: fuse mfma(rt+1)/act(rt) at instruction granularity:
//   per group {1 ds_read -> 4 MFMA -> 1 act row}, pinned with
//   sched_group_barrier (DS_READ 1 / MFMA 4 / VALU 24 / DS_WRITE 1).
//   Math identical to R11 (absmax 4.9e-4). No new registers.
//   TRIPWIRES: VGPR <= 128, WRITE_SIZE ~1MB, LDS 32768 exactly.

typedef _Float16 half8  __attribute__((ext_vector_type(8)));
typedef _Float16 half2v __attribute__((ext_vector_type(2)));
typedef float    floatx4 __attribute__((ext_vector_type(4)));

template <int N> struct ic_t { static constexpr int value = N; };

#define LOG2E 1.44269504088896340736f

__global__ __launch_bounds__(512, 2) void lstm_fused(
    const float* __restrict__ x,    // [B,T,C]
    const float* __restrict__ Wih,  // [C,4H]
    const float* __restrict__ Whh,  // [C,4H,H]
    const float* __restrict__ bih,  // [C,4H]
    const float* __restrict__ bhh,  // [C,4H]
    const float* __restrict__ Wfc,  // [C,H]
    const float* __restrict__ bfc,  // [C]
    float* __restrict__ out)        // [B,C]
{
    constexpr int T = 1024, C = 64, H = 128, G = 512;
    constexpr int TC = T * C;

    // Two h buffers: [4 rowtiles][4 ksteps][64 chunks][8 f16] = 16 KB each.
    // TOTAL LDS = 32768 exactly — do not add a single byte (2-block residency).
    __shared__ _Float16 hbuf[2][8192];

    const int bid = blockIdx.x;
    const int ch  = bid & 63;          // channel
    const int b0  = (bid >> 6) << 6;   // batch tile base: 0,64,...,448

    const int tid = threadIdx.x;
    const int w   = tid >> 6;          // wave 0..7 -> hidden slice [w*16, w*16+16)
    const int l   = tid & 63;
    const int q   = l >> 4;            // quad
    const int li  = l & 15;

    // ---- x addressing: uniform base pointer + per-lane 32-bit offset ----
    const float* xb = x + ch;
    const int rb0 = (b0 + q * 4) * TC;  // per-lane element offset base

    // x staging: two 4-reg buffers, each consumed one full phase after load.
    float xE[4], xO[4];
#pragma unroll
    for (int r = 0; r < 4; ++r) xE[r] = xb[rb0 + r * TC];          // t=0, rt0
#pragma unroll
    for (int r = 0; r < 4; ++r) xO[r] = xb[rb0 + (16 + r) * TC];   // t=0, rt1

    // ---- per-lane constants: packed W_ih+bias (f16), W_hh fragments ----
    half2v wbp[4];
    half8 Wf[4][4];
#pragma unroll
    for (int ct = 0; ct < 4; ++ct) {
        const float sc = (ct == 2) ? 2.0f * LOG2E : LOG2E;  // gate order i,f,g,o
        const int col = ct * H + w * 16 + li;
        wbp[ct][0] = (_Float16)(Wih[ch * G + col] * sc);
        wbp[ct][1] = (_Float16)((bih[ch * G + col] + bhh[ch * G + col]) * sc);
#pragma unroll
        for (int ks = 0; ks < 4; ++ks) {
            const float* wp = &Whh[((size_t)(ch * G + col)) * H + ks * 32 + q * 8];
            half8 hv;
#pragma unroll
            for (int j = 0; j < 8; ++j) hv[j] = (_Float16)(wp[j] * sc);
            Wf[ct][ks] = hv;
        }
    }

    // zero t=0 read buffer (h0 = 0)
    for (int i = tid; i < 8192; i += 512) hbuf[0][i] = (_Float16)0.0f;

    // cell state (fp32 registers): 4 rowtiles x 4 rows
    float cst[4][4];
#pragma unroll
    for (int rt = 0; rt < 4; ++rt)
#pragma unroll
        for (int r = 0; r < 4; ++r) cst[rt][r] = 0.0f;

    // ---- h layout with XOR bank swizzle ----
    // value (batch row m in tile, hidden hh): ks=hh>>5, qq=(hh&31)>>3, j=hh&7
    // chunk c = qq*16 + (m ^ (qq&3)); element = (rt*4+ks)*512 + c*8 + j
    const int ks_w = w >> 1;
    const int qq_w = ((w & 1) << 1) + (li >> 3);
    const int j_w  = li & 7;
    const int rxor = qq_w & 3;
    // write base: bits of (qq_w*16 + q*4), (r^rxor), ks_w*512, j_w are
    // disjoint -> addr(r) = K2 ^ (r*8), K2 = base ^ (rxor<<3).
    const int K2 = (ks_w * 512 + (qq_w * 16 + q * 4) * 8 + j_w) ^ (rxor << 3);
    // read: lane l wants chunk (qq=q, m=li) -> c = q*16 + (li ^ (q&3))
    const int rdoff = (q * 16 + (li ^ (q & 3))) * 8;

    __syncthreads();

    // ---- building blocks (all rt/r strictly compile-time) ----

    // one activation row: acc[.][R] -> h(f16) into wb, updates cst[RT][R]
    auto act_row = [&](auto rtc, auto rc, floatx4 (&acc)[4],
                       _Float16* __restrict__ wb) {
        constexpr int RT = decltype(rtc)::value;
        constexpr int R_ = decltype(rc)::value;
        const float u  = __builtin_amdgcn_exp2f(-acc[0][R_]);
        const float v  = __builtin_amdgcn_exp2f(-acc[1][R_]);
        const float p  = __builtin_amdgcn_exp2f(acc[2][R_]);
        const float wq = __builtin_amdgcn_exp2f(-acc[3][R_]);
        const float Du = 1.0f + u, Dv = 1.0f + v;
        const float Dp = 1.0f + p, Dw = 1.0f + wq;
        const float DuDp = Du * Dp;
        const float Rr = __builtin_amdgcn_rcpf(DuDp * Dv);
        const float cn = Rr * fmaf(cst[RT][R_], DuDp, (p - 1.0f) * Dv);
        cst[RT][R_] = cn;
        const float tq = __builtin_amdgcn_fmed3f(
            cn * (2.0f * LOG2E), -29.0f, 29.0f);
        const float e  = __builtin_amdgcn_exp2f(tq);
        const float R2 = __builtin_amdgcn_rcpf(Dw * (1.0f + e));
        wb[RT * 2048 + (K2 ^ (R_ * 8))] = (_Float16)fmaf(e, R2, -R2);
    };

    auto acc_init = [&](floatx4 (&acc)[4], const float (&xq)[4]) {
#pragma unroll
        for (int ct = 0; ct < 4; ++ct) {
            const float wi = (float)wbp[ct][0];
            const float bb = (float)wbp[ct][1];
#pragma unroll
            for (int r = 0; r < 4; ++r)
                acc[ct][r] = fmaf(xq[r], wi, bb);
        }
    };

    // one interleave group: ds_read + 4 MFMA (rowtile RTM, k-slice G_) fused
    // with one act row (rowtile RTA, row G_). sched_group_barrier pins the
    // emitted order so MFMA and VALU alternate at fine grain.
    auto grp = [&](auto rtM, auto gc, floatx4 (&accM)[4],
                   auto rtA, floatx4 (&accA)[4],
                   const _Float16* __restrict__ rb, _Float16* __restrict__ wb) {
        constexpr int RTM = decltype(rtM)::value;
        constexpr int G_  = decltype(gc)::value;
        const half8 a = *(const half8*)&rb[(RTM * 4 + G_) * 512 + rdoff];
#pragma unroll
        for (int ct = 0; ct < 4; ++ct)
            accM[ct] = __builtin_amdgcn_mfma_f32_16x16x32_f16(a, Wf[ct][G_], accM[ct], 0, 0, 0);
        act_row(rtA, gc, accA, wb);
        __builtin_amdgcn_sched_group_barrier(0x100, 1, 0);  // 1 DS_READ
        __builtin_amdgcn_sched_group_barrier(0x008, 4, 0);  // 4 MFMA
        __builtin_amdgcn_sched_group_barrier(0x002, 24, 0); // ~act row VALU
        __builtin_amdgcn_sched_group_barrier(0x200, 1, 0);  // 1 DS_WRITE
    };

    // fused phase: mfma(rowtile RTM into accM) interleaved with act(RTA, accA)
    auto fused = [&](auto rtM, floatx4 (&accM)[4], const float (&xq)[4],
                     auto rtA, floatx4 (&accA)[4],
                     const _Float16* __restrict__ rb, _Float16* __restrict__ wb) {
        acc_init(accM, xq);
        grp(rtM, ic_t<0>{}, accM, rtA, accA, rb, wb);
        grp(rtM, ic_t<1>{}, accM, rtA, accA, rb, wb);
        grp(rtM, ic_t<2>{}, accM, rtA, accA, rb, wb);
        grp(rtM, ic_t<3>{}, accM, rtA, accA, rb, wb);
    };

    auto mfma_only = [&](auto rtc, floatx4 (&acc)[4],
                         const _Float16* __restrict__ rb, const float (&xq)[4]) {
        constexpr int rt = decltype(rtc)::value;
        acc_init(acc, xq);
#pragma unroll
        for (int ks = 0; ks < 4; ++ks) {
            const half8 a = *(const half8*)&rb[(rt * 4 + ks) * 512 + rdoff];
#pragma unroll
            for (int ct = 0; ct < 4; ++ct)
                acc[ct] = __builtin_amdgcn_mfma_f32_16x16x32_f16(a, Wf[ct][ks], acc[ct], 0, 0, 0);
        }
    };

    auto act_only = [&](auto rtc, floatx4 (&acc)[4], _Float16* __restrict__ wb) {
        act_row(rtc, ic_t<0>{}, acc, wb);
        act_row(rtc, ic_t<1>{}, acc, wb);
        act_row(rtc, ic_t<2>{}, acc, wb);
        act_row(rtc, ic_t<3>{}, acc, wb);
    };

    auto load_x = [&](float (&xq)[4], const float* base, int off) {
#pragma unroll
        for (int r = 0; r < 4; ++r) xq[r] = base[rb0 + off + r * TC];
    };

    auto step = [&](const _Float16* __restrict__ rb, _Float16* __restrict__ wb,
                    const float* xt, const float* xtn) {
        floatx4 accA[4], accB[4];
        // PRO: mfma(0) alone
        mfma_only(ic_t<0>{}, accA, rb, xE);
        load_x(xE, xt, 32 * TC);            // x(t, rt2)
        // P0: mfma(1,B) interleaved with act(0,A)
        fused(ic_t<1>{}, accB, xO, ic_t<0>{}, accA, rb, wb);
        load_x(xO, xt, 48 * TC);            // x(t, rt3)
        // P1: mfma(2,A) interleaved with act(1,B)
        fused(ic_t<2>{}, accA, xE, ic_t<1>{}, accB, rb, wb);
        load_x(xE, xtn, 0);                 // x(t+1, rt0)
        // P2: mfma(3,B) interleaved with act(2,A)
        fused(ic_t<3>{}, accB, xO, ic_t<2>{}, accA, rb, wb);
        load_x(xO, xtn, 16 * TC);           // x(t+1, rt1)
        // P3: act(3,B) alone
        act_only(ic_t<3>{}, accB, wb);
        __syncthreads();
    };

    const float* xt = xb;
    for (int t = 0; t < T; t += 2) {
        const float* x1 = xt + C;                       // t+1 (t <= T-2)
        const float* x2 = (t + 2 < T) ? x1 + C : x1;    // t+2, clamped in-bounds
        step(hbuf[0], hbuf[1], xt, x1);
        step(hbuf[1], hbuf[0], x1, x2);
        xt = x2;
    }

    // ---- epilogue: out[b0+row, ch] = h_final . Wfc[ch] + bfc[ch] ----
    // T even -> final h is in hbuf[0]; last __syncthreads already done.
    if (tid < 64) {
        const int row = tid;
        const int rt = row >> 4, m = row & 15;
        float s = bfc[ch];
#pragma unroll
        for (int hh = 0; hh < H; ++hh) {
            const int ks = hh >> 5, qq = (hh & 31) >> 3, j = hh & 7;
            const int c = qq * 16 + (m ^ (qq & 3));
            s += (float)hbuf[0][(rt * 4 + ks) * 512 + c * 8 + j] * Wfc[ch * H + hh];
        }
        out[(size_t)(b0 + row) * C + ch] = s;
    }
}

extern "C" void kernel_launch(void* const* d_in, const int* in_sizes, int n_in,
                              void* d_out, int out_size, void* d_ws, size_t ws_size,
                              hipStream_t stream) {
    const float* x   = (const float*)d_in[0];
    const float* Wih = (const float*)d_in[1];
    const float* Whh = (const float*)d_in[2];
    const float* bih = (const float*)d_in[3];
    const float* bhh = (const float*)d_in[4];
    const float* Wfc = (const float*)d_in[5];
    const float* bfc = (const float*)d_in[6];
    float* out = (float*)d_out;

    lstm_fused<<<512, 512, 0, stream>>>(x, Wih, Whh, bih, bhh, Wfc, bfc, out);
}

// Round 8
// 5483.701 us; speedup vs baseline: 1.2248x; 1.2248x over previous
//
#include <hip/hip_runtime.h>

// Per-channel LSTM (input_size=1) + per-channel Linear(H,1), fully fused.
// B=512, T=1024, C=64, H=128.
// Round 14: resubmit of R13 (infra failure, kernel never ran).
//   R11 (best, 5504us) + cross-block phase skew (hypothesis test).
//   Evidence: across R6/R11/R12, MfmaUtil+VALUBusy+idle == 100% for three
//   different schedules -> MFMA and VALU never overlap. Two models:
//     H1 lockstep: 4 waves/SIMD (2 per block x 2 blocks) phase-aligned;
//        both blocks contention-locked. Fix: skew odd blocks by ~1500 cyc
//        (one-time dependent-FMA delay), so block A's act burst overlaps
//        block B's MFMA burst. Per-block barriers preserve the offset.
//     H2 serial issue port: gfx950 SIMD serializes MFMA+VALU issue; sum=100%
//        is a HW identity; 12.9k cyc/step is the floor (9.0k VALU + 4.1k
//        MFMA). Skew changes nothing (port cycles conserved) -> roofline.
//   TRIPWIRES: VGPR=128, WRITE_SIZE~1024KB, LDS=32768 exactly.

typedef _Float16 half8  __attribute__((ext_vector_type(8)));
typedef _Float16 half2v __attribute__((ext_vector_type(2)));
typedef float    floatx4 __attribute__((ext_vector_type(4)));

template <int N> struct ic_t { static constexpr int value = N; };

#define LOG2E 1.44269504088896340736f

__global__ __launch_bounds__(512, 2) void lstm_fused(
    const float* __restrict__ x,    // [B,T,C]
    const float* __restrict__ Wih,  // [C,4H]
    const float* __restrict__ Whh,  // [C,4H,H]
    const float* __restrict__ bih,  // [C,4H]
    const float* __restrict__ bhh,  // [C,4H]
    const float* __restrict__ Wfc,  // [C,H]
    const float* __restrict__ bfc,  // [C]
    float* __restrict__ out)        // [B,C]
{
    constexpr int T = 1024, C = 64, H = 128, G = 512;
    constexpr int TC = T * C;

    // Two h buffers: [4 rowtiles][4 ksteps][64 chunks][8 f16] = 16 KB each.
    // TOTAL LDS = 32768 exactly — do not add a single byte (2-block residency).
    __shared__ _Float16 hbuf[2][8192];

    const int bid = blockIdx.x;
    const int ch  = bid & 63;          // channel
    const int b0  = (bid >> 6) << 6;   // batch tile base: 0,64,...,448

    const int tid = threadIdx.x;
    const int w   = tid >> 6;          // wave 0..7 -> hidden slice [w*16, w*16+16)
    const int l   = tid & 63;
    const int q   = l >> 4;            // quad
    const int li  = l & 15;

    // ---- x addressing: uniform base pointer + per-lane 32-bit offset ----
    const float* xb = x + ch;
    const int rb0 = (b0 + q * 4) * TC;  // per-lane element offset base

    // x staging: two 4-reg buffers, each consumed one full phase after load.
    float xE[4], xO[4];
#pragma unroll
    for (int r = 0; r < 4; ++r) xE[r] = xb[rb0 + r * TC];          // t=0, rt0
#pragma unroll
    for (int r = 0; r < 4; ++r) xO[r] = xb[rb0 + (16 + r) * TC];   // t=0, rt1

    // ---- per-lane constants: packed W_ih+bias (f16), W_hh fragments ----
    half2v wbp[4];
    half8 Wf[4][4];
#pragma unroll
    for (int ct = 0; ct < 4; ++ct) {
        const float sc = (ct == 2) ? 2.0f * LOG2E : LOG2E;  // gate order i,f,g,o
        const int col = ct * H + w * 16 + li;
        wbp[ct][0] = (_Float16)(Wih[ch * G + col] * sc);
        wbp[ct][1] = (_Float16)((bih[ch * G + col] + bhh[ch * G + col]) * sc);
#pragma unroll
        for (int ks = 0; ks < 4; ++ks) {
            const float* wp = &Whh[((size_t)(ch * G + col)) * H + ks * 32 + q * 8];
            half8 hv;
#pragma unroll
            for (int j = 0; j < 8; ++j) hv[j] = (_Float16)(wp[j] * sc);
            Wf[ct][ks] = hv;
        }
    }

    // zero t=0 read buffer (h0 = 0)
    for (int i = tid; i < 8192; i += 512) hbuf[0][i] = (_Float16)0.0f;

    // cell state (fp32 registers): 4 rowtiles x 4 rows
    float cst[4][4];
#pragma unroll
    for (int rt = 0; rt < 4; ++rt)
#pragma unroll
        for (int r = 0; r < 4; ++r) cst[rt][r] = 0.0f;

    // ---- h layout with XOR bank swizzle ----
    // value (batch row m in tile, hidden hh): ks=hh>>5, qq=(hh&31)>>3, j=hh&7
    // chunk c = qq*16 + (m ^ (qq&3)); element = (rt*4+ks)*512 + c*8 + j
    const int ks_w = w >> 1;
    const int qq_w = ((w & 1) << 1) + (li >> 3);
    const int j_w  = li & 7;
    const int rxor = qq_w & 3;
    // write base: bits of (qq_w*16 + q*4), (r^rxor), ks_w*512, j_w are
    // disjoint -> addr(r) = K2 ^ (r*8), K2 = base ^ (rxor<<3).
    const int K2 = (ks_w * 512 + (qq_w * 16 + q * 4) * 8 + j_w) ^ (rxor << 3);
    // read: lane l wants chunk (qq=q, m=li) -> c = q*16 + (li ^ (q&3))
    const int rdoff = (q * 16 + (li ^ (q & 3))) * 8;

    __syncthreads();

    // ---- cross-block phase skew: odd blocks delay ~1500 cyc (one-time) ----
    // Block-uniform branch (no divergence); barriers below are identical for
    // all blocks, so the offset persists via per-block barrier semantics.
    {
        int n;
        asm volatile("v_mov_b32 %0, %1" : "=v"(n) : "v"((bid & 1) ? 375 : 0));
        float d0 = (float)(l + 1);
#pragma unroll 1
        for (int i = 0; i < n; ++i)
            d0 = fmaf(d0, 1.0000001f, 1.0f);   // dependent chain, ~4 cyc each
        asm volatile("" :: "v"(d0));           // keep live (rule #17)
    }

    // ---- phase building blocks (rt strictly compile-time) ----
    auto mfma_rt = [&](auto rtc, floatx4 (&acc)[4], const _Float16* __restrict__ rb,
                       const float (&xq)[4]) {
        constexpr int rt = decltype(rtc)::value;
#pragma unroll
        for (int ct = 0; ct < 4; ++ct) {
            const float wi = (float)wbp[ct][0];
            const float bb = (float)wbp[ct][1];
#pragma unroll
            for (int r = 0; r < 4; ++r)
                acc[ct][r] = fmaf(xq[r], wi, bb);
        }
#pragma unroll
        for (int ks = 0; ks < 4; ++ks) {
            const half8 a = *(const half8*)&rb[(rt * 4 + ks) * 512 + rdoff];
#pragma unroll
            for (int ct = 0; ct < 4; ++ct)
                acc[ct] = __builtin_amdgcn_mfma_f32_16x16x32_f16(a, Wf[ct][ks], acc[ct], 0, 0, 0);
        }
    };

    auto act_rt = [&](auto rtc, floatx4 (&acc)[4], _Float16* __restrict__ wb) {
        constexpr int rt = decltype(rtc)::value;
        // activations (preacts prescaled by log2e; g by 2*log2e):
        //   sig(i)=1/Du, sig(f)=1/Dv, tanh(g)=(p-1)/Dp, sig(o)=1/Dw
        //   c' = [c*Du*Dp + (p-1)*Dv] * rcp(Du*Dv*Dp)
        //   h' = sig(o)*tanh(c') = (e-1) * rcp(Dw*(1+e)), e=exp2(clamped)
#pragma unroll
        for (int r = 0; r < 4; ++r) {
            const float u  = __builtin_amdgcn_exp2f(-acc[0][r]);
            const float v  = __builtin_amdgcn_exp2f(-acc[1][r]);
            const float p  = __builtin_amdgcn_exp2f(acc[2][r]);
            const float wq = __builtin_amdgcn_exp2f(-acc[3][r]);
            const float Du = 1.0f + u, Dv = 1.0f + v;
            const float Dp = 1.0f + p, Dw = 1.0f + wq;
            const float DuDp = Du * Dp;
            const float R  = __builtin_amdgcn_rcpf(DuDp * Dv);
            const float cn = R * fmaf(cst[rt][r], DuDp, (p - 1.0f) * Dv);
            cst[rt][r] = cn;
            // tanh(cn): clamp exp2 arg to +-29 (tanh saturates to 1.0f)
            const float tq = __builtin_amdgcn_fmed3f(
                cn * (2.0f * LOG2E), -29.0f, 29.0f);
            const float e  = __builtin_amdgcn_exp2f(tq);
            const float R2 = __builtin_amdgcn_rcpf(Dw * (1.0f + e));
            wb[rt * 2048 + (K2 ^ (r * 8))] = (_Float16)fmaf(e, R2, -R2);
        }
    };

    auto load_x = [&](float (&xq)[4], const float* base, int off) {
#pragma unroll
        for (int r = 0; r < 4; ++r) xq[r] = base[rb0 + off + r * TC];
    };

    auto step = [&](const _Float16* __restrict__ rb, _Float16* __restrict__ wb,
                    const float* xt, const float* xtn) {
        floatx4 accA[4], accB[4];
        // PRO
        mfma_rt(ic_t<0>{}, accA, rb, xE);
        load_x(xE, xt, 32 * TC);            // x(t, rt2)
        // P0
        mfma_rt(ic_t<1>{}, accB, rb, xO);
        load_x(xO, xt, 48 * TC);            // x(t, rt3)
        act_rt(ic_t<0>{}, accA, wb);
        // P1
        mfma_rt(ic_t<2>{}, accA, rb, xE);
        load_x(xE, xtn, 0);                 // x(t+1, rt0)
        act_rt(ic_t<1>{}, accB, wb);
        // P2
        mfma_rt(ic_t<3>{}, accB, rb, xO);
        load_x(xO, xtn, 16 * TC);           // x(t+1, rt1)
        act_rt(ic_t<2>{}, accA, wb);
        // P3
        act_rt(ic_t<3>{}, accB, wb);
        __syncthreads();
    };

    const float* xt = xb;
    for (int t = 0; t < T; t += 2) {
        const float* x1 = xt + C;                       // t+1 (t <= T-2)
        const float* x2 = (t + 2 < T) ? x1 + C : x1;    // t+2, clamped in-bounds
        step(hbuf[0], hbuf[1], xt, x1);
        step(hbuf[1], hbuf[0], x1, x2);
        xt = x2;
    }

    // ---- epilogue: out[b0+row, ch] = h_final . Wfc[ch] + bfc[ch] ----
    // T even -> final h is in hbuf[0]; last __syncthreads already done.
    if (tid < 64) {
        const int row = tid;
        const int rt = row >> 4, m = row & 15;
        float s = bfc[ch];
#pragma unroll
        for (int hh = 0; hh < H; ++hh) {
            const int ks = hh >> 5, qq = (hh & 31) >> 3, j = hh & 7;
            const int c = qq * 16 + (m ^ (qq & 3));
            s += (float)hbuf[0][(rt * 4 + ks) * 512 + c * 8 + j] * Wfc[ch * H + hh];
        }
        out[(size_t)(b0 + row) * C + ch] = s;
    }
}

extern "C" void kernel_launch(void* const* d_in, const int* in_sizes, int n_in,
                              void* d_out, int out_size, void* d_ws, size_t ws_size,
                              hipStream_t stream) {
    const float* x   = (const float*)d_in[0];
    const float* Wih = (const float*)d_in[1];
    const float* Whh = (const float*)d_in[2];
    const float* bih = (const float*)d_in[3];
    const float* bhh = (const float*)d_in[4];
    const float* Wfc = (const float*)d_in[5];
    const float* bfc = (const float*)d_in[6];
    float* out = (float*)d_out;

    lstm_fused<<<512, 512, 0, stream>>>(x, Wih, Whh, bih, bhh, Wfc, bfc, out);
}